// Round 15
// baseline (437.370 us; speedup 1.0000x reference)
//
#include <hip/hip_runtime.h>
#include <cstdint>
#include <cmath>

// Problem constants (B,S,D,F,E,K,H = 4,1024,512,2048,8,2,8; HEAD_DIM=64)
#define Bc 4
#define Sc 1024
#define Dc 512
#define Fc 2048
#define Ec 8
#define Hc 8
#define Mc 4096  // B*S

typedef unsigned short u16;
typedef __attribute__((ext_vector_type(8))) short bf16x8;  // 8 bf16 = 4 VGPRs
typedef __attribute__((ext_vector_type(4))) float f32x4;

__device__ __forceinline__ float bf2f(u16 u) {
  unsigned v = ((unsigned)u) << 16;
  return __builtin_bit_cast(float, v);
}
__device__ __forceinline__ u16 f2bf(float f) {
  unsigned u = __builtin_bit_cast(unsigned, f);
  unsigned r = 0x7fffu + ((u >> 16) & 1u);
  return (u16)((u + r) >> 16);
}
__device__ __forceinline__ unsigned pack2bf(float a, float b) {
  return (unsigned)f2bf(a) | ((unsigned)f2bf(b) << 16);
}
// tanh-approx GELU (max abs err ~3e-4 vs exact erf-GELU; threshold headroom is ~0.07)
__device__ __forceinline__ float gelu_f(float x) {
  const float z = 1.5957691216057308f * fmaf(0.044715f * x, x * x, x);  // 2*sqrt(2/pi)*(x+c x^3)
  const float e = __expf(z);
  return x * (1.0f - __builtin_amdgcn_rcpf(e + 1.0f));
}
// async global->LDS, 16B per lane; LDS dest = base + lane*16 (wave-uniform base)
__device__ __forceinline__ void async16(const void* g, void* l) {
  __builtin_amdgcn_global_load_lds(
      (const __attribute__((address_space(1))) unsigned int*)g,
      (__attribute__((address_space(3))) unsigned int*)l, 16, 0, 0);
}

// T4 counted-vmcnt primitives: keep the just-issued prefetch in flight across barriers.
// "memory" clobbers order LDS/VMEM ops at IR level; sched_barrier(0) blocks MI hoisting
// (learn_hip rule #18). vmcnt is in-order (m135): <=8 outstanding => oldest stage done.
#define VMCNT8() asm volatile("s_waitcnt vmcnt(8)" ::: "memory")
#define VMCNT0() asm volatile("s_waitcnt vmcnt(0)" ::: "memory")
#define SBAR()   asm volatile("s_barrier" ::: "memory")

// fused f32 -> bf16 conversion for all 5 input tensors (single launch; each block does 1024 elems)
__global__ __launch_bounds__(256) void cvt5_kernel(const float* __restrict__ p0, u16* __restrict__ q0,
                                                   const float* __restrict__ p1, u16* __restrict__ q1,
                                                   const float* __restrict__ p2, u16* __restrict__ q2,
                                                   const float* __restrict__ p3, u16* __restrict__ q3,
                                                   const float* __restrict__ p4, u16* __restrict__ q4) {
  int bx = blockIdx.x;
  const float* in;
  u16* outp;
  if (bx < 2048) { in = p0; outp = q0; }                       // x: 2,097,152
  else if (bx < 8192) { in = p1; outp = q1; bx -= 2048; }      // Wqkv: 6,291,456
  else if (bx < 10240) { in = p2; outp = q2; bx -= 8192; }     // Wo: 2,097,152
  else if (bx < 18432) { in = p3; outp = q3; bx -= 10240; }    // W1: 8,388,608
  else { in = p4; outp = q4; bx -= 18432; }                    // W2: 8,388,608
  const long long i = ((long long)bx * 256 + threadIdx.x) * 4;
  const float4 v = *(const float4*)(in + i);
  ushort4 o;
  o.x = f2bf(v.x); o.y = f2bf(v.y); o.z = f2bf(v.z); o.w = f2bf(v.w);
  *(ushort4*)(outp + i) = o;
}

// ---------------- gating precompute: weq[e][d] = sum_j eq[e][j] * gWk[j][d] ----------------
// Block (0, e) additionally computes beq[e] = <gbk, eq[e]> (folds the old beq_kernel launch).
__global__ __launch_bounds__(256) void weq_kernel(const float* __restrict__ gWk,
                                                  const float* __restrict__ eq,
                                                  const float* __restrict__ gbk,
                                                  float* __restrict__ weq,
                                                  float* __restrict__ beq) {
  __shared__ float red[4][64];
  const int tid = threadIdx.x, wave = tid >> 6, lane = tid & 63;
  const int d = blockIdx.x * 64 + lane;
  const int e = blockIdx.y;
  float acc = 0.f;
  for (int j = wave * 128; j < wave * 128 + 128; ++j)
    acc += gWk[(long long)j * 512 + d] * eq[e * 512 + j];
  red[wave][lane] = acc;
  __syncthreads();
  if (wave == 0)
    weq[e * 512 + d] = red[0][lane] + red[1][lane] + red[2][lane] + red[3][lane];
  if (blockIdx.x == 0 && wave == 1) {
    float a = 0.f;
#pragma unroll
    for (int i = 0; i < 8; ++i) a += gbk[lane + 64 * i] * eq[e * 512 + lane + 64 * i];
#pragma unroll
    for (int off = 32; off; off >>= 1) a += __shfl_xor(a, off);
    if (lane == 0) beq[e] = a;
  }
}

// ---- gating pass 1: scores = (x@weq^T + beq)*D^-0.5, softmax(E=8), top-2, renorm.   ----
// Writes gated[t][8] + emask[t] (bit e set if expert e selected). NO ATOMICS (R10: the
// old dependent atomicAdds on one 128B region serialized through one L2 slice, 54.8us).
__global__ __launch_bounds__(256) void gate_kernel(const float* __restrict__ x,
                                                   const float* __restrict__ weq,
                                                   const float* __restrict__ beq,
                                                   float* __restrict__ gated,
                                                   int* __restrict__ emask) {
  const int wave = threadIdx.x >> 6, lane = threadIdx.x & 63;
  const int t = blockIdx.x * 4 + wave;
  const float* xr = x + (long long)t * 512;
  float acc[8] = {};
#pragma unroll
  for (int i = 0; i < 8; ++i) {
    const float xv = xr[lane + 64 * i];
#pragma unroll
    for (int e2 = 0; e2 < 8; ++e2) acc[e2] += xv * weq[e2 * 512 + lane + 64 * i];
  }
#pragma unroll
  for (int e2 = 0; e2 < 8; ++e2)
#pragma unroll
    for (int off = 32; off; off >>= 1) acc[e2] += __shfl_xor(acc[e2], off);
  if (lane == 0) {
    const float scale = 0.044194173824159216f;  // 512^-0.5
    float s[8], mx = -1e30f;
#pragma unroll
    for (int e2 = 0; e2 < 8; ++e2) { s[e2] = (acc[e2] + beq[e2]) * scale; mx = fmaxf(mx, s[e2]); }
    float p[8], sum = 0.f;
#pragma unroll
    for (int e2 = 0; e2 < 8; ++e2) { p[e2] = expf(s[e2] - mx); sum += p[e2]; }
#pragma unroll
    for (int e2 = 0; e2 < 8; ++e2) p[e2] /= sum;
    int i1 = 0;
#pragma unroll
    for (int e2 = 1; e2 < 8; ++e2) if (p[e2] > p[i1]) i1 = e2;
    int i2 = (i1 == 0) ? 1 : 0;
#pragma unroll
    for (int e2 = 0; e2 < 8; ++e2) if (e2 != i1 && e2 != i2 && p[e2] > p[i2]) i2 = e2;
    const float denom = p[i1] + p[i2] + 1e-9f;
#pragma unroll
    for (int e2 = 0; e2 < 8; ++e2)
      gated[t * 8 + e2] = (e2 == i1 || e2 == i2) ? p[e2] / denom : 0.f;
    emask[t] = (1 << i1) | (1 << i2);
  }
}

// ---- gating pass 2: deterministic routing-list build. One block per (e,b) segment;   ----
// ballot-based prefix sum over the segment's 1024 tokens (token order) -> tlist/pos/cnt,
// then pad tlist to a multiple of 128 with a valid token (row 0 of sequence b).
__global__ __launch_bounds__(256) void build_kernel(const int* __restrict__ emask,
                                                    int* __restrict__ cnt,
                                                    int* __restrict__ tlist,
                                                    int* __restrict__ pos) {
  const int seg = blockIdx.x;  // e*4 + b
  const int e = seg >> 2, b = seg & 3;
  const int tid = threadIdx.x, wave = tid >> 6, lane = tid & 63;
  __shared__ int wbase[4];
  __shared__ int running;
  if (tid == 0) running = 0;
  __syncthreads();
  for (int i0 = 0; i0 < 1024; i0 += 256) {
    const int t = (b << 10) + i0 + tid;
    const int flag = (emask[t] >> e) & 1;
    const unsigned long long m = __ballot(flag);
    const int prefix = __popcll(m & ((1ULL << lane) - 1ULL));
    if (lane == 0) wbase[wave] = __popcll(m);
    __syncthreads();
    int base = running;
    for (int w = 0; w < wave; ++w) base += wbase[w];
    if (flag) {
      const int p = base + prefix;
      tlist[seg * 1024 + p] = t;
      pos[e * 4096 + t] = p;
    }
    __syncthreads();
    if (tid == 0) running += wbase[0] + wbase[1] + wbase[2] + wbase[3];
    __syncthreads();
  }
  const int c = running;  // final (all threads see it after the last barrier)
  if (tid == 0) cnt[seg] = c;
  const int ce = (c + 127) & ~127;
  const int tpad = b << 10;
  for (int i = c + tid; i < ce; i += 256) tlist[seg * 1024 + i] = tpad;
}

// ---- work lists (all compacted so active blocks are contiguous in linear block id):  ----
// wl[0..95]   : 128-row tiles (seg<<8|tile), total at wl[96]
// wl[97]      : total 64-row tiles; wl[128..319]: 64-row tiles (seg<<8|tile)
// wl[104+e]   : per-expert 128-row tile count; wl[320+e*32+j]: expert e's tiles
__global__ void wl_kernel(const int* __restrict__ cnt, int* __restrict__ wl) {
  const int tid = threadIdx.x;
  if (tid < 32) {
    const int seg = tid;
    int base = 0;
    for (int s = 0; s < seg; ++s) base += (cnt[s] + 127) >> 7;
    const int nt = (cnt[seg] + 127) >> 7;
    for (int t = 0; t < nt; ++t) wl[base + t] = (seg << 8) | t;
    for (int t = 0; t < 2 * nt; ++t) wl[128 + 2 * base + t] = (seg << 8) | t;
    if (seg == 31) { wl[96] = base + nt; wl[97] = 2 * (base + nt); }
  } else if (tid < 40) {
    const int e = tid - 32;
    int n = 0;
    for (int b = 0; b < 4; ++b) {
      const int seg = e * 4 + b;
      const int nt = (cnt[seg] + 127) >> 7;
      for (int t = 0; t < nt; ++t) wl[320 + e * 32 + n++] = (seg << 8) | t;
    }
    wl[104 + e] = n;
  }
}

// ---------------- bf16 MFMA GEMM: C[m,n] = sum_k A[m,k]*Bt[n,k] + bias[n] ----------------
// 128x128 tile, 4 waves each 64x64 (4x4 of 16x16x32 MFMA), 2-buffer LDS pipeline with
// T4 COUNTED vmcnt: {stage(next); vmcnt(8); sbar; compute(cur); sbar} -- the 8 just-issued
// loads stay in flight ACROSS both barriers (old __syncthreads drained vmcnt to 0 every
// step, serializing the prefetch; m218 measured counted-vs-drain0 = +38-73%).
// Correctness: buffer restaged at step s+1 is the one computed at step s (trailing sbar
// separates); all waves execute the same vmcnt(8) before the shared sbar, so the oldest
// stage is globally complete at barrier exit (vmcnt retires in order, m135).
// EPI=2: merged KV launch, grid (32,8,8): bn<512 -> k path, bn>=512 -> v path (swapped
// MFMA operands -> coalesced transposed-vT stores).
// ROUTED=3: expert->XCD-pinned grid dim3(8, 32, N/128): blockIdx.x = expert -> XCD;
// W1_e + A_e L2-resident (FETCH 81->17 MB, R9).
template <int GELU, int EPI, int ROUTED, int BK>
__global__ __launch_bounds__(256) void gemm_bf16(
    const u16* __restrict__ A, const u16* __restrict__ Bw, const float* __restrict__ bias,
    u16* __restrict__ Cout, u16* __restrict__ vT, int M, int N, int K, long long Astride,
    long long Bstride, const int* __restrict__ wl) {
  int e;
  long long bm, bn;
  if (ROUTED == 1) {
    const int total = wl[96];
    if ((int)blockIdx.x >= total) return;
    const int item = wl[blockIdx.x];
    const int seg = item >> 8, tile = item & 255;
    e = seg >> 2;
    bm = ((long long)(seg & 3) << 10) + tile * 128;
    bn = (long long)blockIdx.y * 128;
  } else if (ROUTED == 3) {
    e = blockIdx.x;  // 0..7, linear id % 8 == e (gridDim.x == 8)
    if ((int)blockIdx.y >= wl[104 + e]) return;
    const int item = wl[320 + e * 32 + blockIdx.y];
    const int seg = item >> 8, tile = item & 255;
    bm = ((long long)(seg & 3) << 10) + tile * 128;
    bn = (long long)blockIdx.z * 128;
  } else {
    e = blockIdx.z;
    bm = (long long)blockIdx.x * 128;
    bn = (long long)blockIdx.y * 128;
  }
  __shared__ __attribute__((aligned(16))) u16 As[2][128 * BK];
  __shared__ __attribute__((aligned(16))) u16 Bs[2][128 * BK];
  const int tid = threadIdx.x;
  const int wave = tid >> 6, lane = tid & 63;
  const u16* Ag = A + (long long)e * Astride + bm * K;
  const u16* Bg = Bw + ((long long)e * Bstride + bn) * K;
  constexpr int LPR = BK / 8;   // lanes per row in a staging instruction
  constexpr int RPI = 512 / BK; // rows per staging instruction
  constexpr int IPW = BK / 16;  // staging instructions per wave (each of A and B)
  const int lrow = lane / LPR, lpos = lane % LPR;
  const int lm = lane & 15, quad = lane >> 4;
  const int wm = (wave >> 1) * 64, wn = (wave & 1) * 64;
  const bool isv = (EPI == 2) && (bn >= 512);
  f32x4 acc[4][4] = {};

  auto stage = [&](int buf, int kk) {
#pragma unroll
    for (int i = 0; i < IPW; ++i) {
      const int gi = wave * IPW + i;        // instruction slot 0..BK/4-1
      const int row = gi * RPI + lrow;      // tile row 0..127
      const int sc = lpos ^ (row & 7);      // XOR-swizzled source chunk
      async16(Ag + (long long)row * K + kk + sc * 8, &As[buf][gi * 512]);
      async16(Bg + (long long)row * K + kk + sc * 8, &Bs[buf][gi * 512]);
    }
  };
  auto computeN = [&](int buf) {  // normal operand order: lane owns output rows
#pragma unroll
    for (int ks = 0; ks < BK / 32; ++ks) {
      bf16x8 af[4], bfr[4];
#pragma unroll
      for (int mi = 0; mi < 4; ++mi) {
        const int row = wm + mi * 16 + lm;
        const int ch = (ks * 4 + quad) ^ (row & 7);
        af[mi] = *(const bf16x8*)(&As[buf][row * BK + ch * 8]);
      }
#pragma unroll
      for (int nj = 0; nj < 4; ++nj) {
        const int row = wn + nj * 16 + lm;
        const int ch = (ks * 4 + quad) ^ (row & 7);
        bfr[nj] = *(const bf16x8*)(&Bs[buf][row * BK + ch * 8]);
      }
#pragma unroll
      for (int mi = 0; mi < 4; ++mi)
#pragma unroll
        for (int nj = 0; nj < 4; ++nj)
          acc[mi][nj] = __builtin_amdgcn_mfma_f32_16x16x32_bf16(bfr[nj], af[mi], acc[mi][nj], 0, 0, 0);
    }
  };
  auto computeV = [&](int buf) {  // swapped operand order: lane owns output cols
#pragma unroll
    for (int ks = 0; ks < BK / 32; ++ks) {
      bf16x8 af[4], bfr[4];
#pragma unroll
      for (int mi = 0; mi < 4; ++mi) {
        const int row = wm + mi * 16 + lm;
        const int ch = (ks * 4 + quad) ^ (row & 7);
        af[mi] = *(const bf16x8*)(&As[buf][row * BK + ch * 8]);
      }
#pragma unroll
      for (int nj = 0; nj < 4; ++nj) {
        const int row = wn + nj * 16 + lm;
        const int ch = (ks * 4 + quad) ^ (row & 7);
        bfr[nj] = *(const bf16x8*)(&Bs[buf][row * BK + ch * 8]);
      }
#pragma unroll
      for (int mi = 0; mi < 4; ++mi)
#pragma unroll
        for (int nj = 0; nj < 4; ++nj)
          acc[mi][nj] = __builtin_amdgcn_mfma_f32_16x16x32_bf16(af[mi], bfr[nj], acc[mi][nj], 0, 0, 0);
    }
  };

  // counted-vmcnt double-buffered K-loop (2 steps per iteration; K/BK even here)
  stage(0, 0);
  if (!isv) {
    for (int kk = 0; kk < K; kk += 2 * BK) {
      // step A: compute buf0
      if (kk + BK < K) { stage(1, kk + BK); VMCNT8(); } else { VMCNT0(); }
      __builtin_amdgcn_sched_barrier(0);
      SBAR();
      computeN(0);
      SBAR();
      // step B: compute buf1
      if (kk + BK < K) {
        if (kk + 2 * BK < K) { stage(0, kk + 2 * BK); VMCNT8(); } else { VMCNT0(); }
        __builtin_amdgcn_sched_barrier(0);
        SBAR();
        computeN(1);
        SBAR();
      }
    }
  } else {
    for (int kk = 0; kk < K; kk += 2 * BK) {
      if (kk + BK < K) { stage(1, kk + BK); VMCNT8(); } else { VMCNT0(); }
      __builtin_amdgcn_sched_barrier(0);
      SBAR();
      computeV(0);
      SBAR();
      if (kk + BK < K) {
        if (kk + 2 * BK < K) { stage(0, kk + 2 * BK); VMCNT8(); } else { VMCNT0(); }
        __builtin_amdgcn_sched_barrier(0);
        SBAR();
        computeV(1);
        SBAR();
      }
    }
  }

  const float* bs = bias + (long long)e * Bstride;
  if (isv) {
    // v epilogue: lane owns col n (v d-dim = n-512), 4 consecutive rows m0 (tokens)
#pragma unroll
    for (int nj = 0; nj < 4; ++nj) {
      const int n = (int)bn + wn + nj * 16 + lm;  // 512..1023
      const float bvs = bs[n];
      const int hh = (n - 512) >> 6, dd = (n - 512) & 63;
#pragma unroll
      for (int mi = 0; mi < 4; ++mi) {
        const int m0 = (int)bm + wm + mi * 16 + quad * 4;
        const int bb = m0 >> 10, ss = m0 & 1023;
        uint2 pk;
        pk.x = pack2bf(acc[mi][nj][0] + bvs, acc[mi][nj][1] + bvs);
        pk.y = pack2bf(acc[mi][nj][2] + bvs, acc[mi][nj][3] + bvs);
        *(uint2*)(vT + ((((long long)e * Bc + bb) * Hc + hh) * 64 + dd) * Sc + ss) = pk;
      }
    }
    return;
  }
  // generic epilogue (also the k path of EPI=2): lane owns row m, 4 consecutive cols n0
#pragma unroll
  for (int mi = 0; mi < 4; ++mi) {
    const int m = (int)bm + wm + mi * 16 + lm;
#pragma unroll
    for (int nj = 0; nj < 4; ++nj) {
      const int n0 = (int)bn + wn + nj * 16 + quad * 4;
      const float4 bv = *(const float4*)(bs + n0);
      float v0 = acc[mi][nj][0] + bv.x;
      float v1 = acc[mi][nj][1] + bv.y;
      float v2 = acc[mi][nj][2] + bv.z;
      float v3 = acc[mi][nj][3] + bv.w;
      if (GELU) { v0 = gelu_f(v0); v1 = gelu_f(v1); v2 = gelu_f(v2); v3 = gelu_f(v3); }
      uint2 pk; pk.x = pack2bf(v0, v1); pk.y = pack2bf(v2, v3);
      *(uint2*)(Cout + ((long long)e * M + m) * N + n0) = pk;
    }
  }
}

// ---------------- 64-row routed GEMM: 64x128 tile, BK param, 4 waves each 64x32 ----------------
// For the N=512 routed GEMMs (Q, Wo, W2).
// A is compact p-space (p = seg*1024 + row) or token-gathered via tlist (GATHER).
template <int GELU, int GATHER, int BK>
__global__ __launch_bounds__(256) void gemm64_bf16(
    const u16* __restrict__ A, const u16* __restrict__ Bw, const float* __restrict__ bias,
    u16* __restrict__ Cout, int N, int K, long long Bstride,
    const int* __restrict__ wl, const int* __restrict__ tlist) {
  if ((int)blockIdx.x >= wl[97]) return;
  const int item = wl[128 + blockIdx.x];
  const int seg = item >> 8, tile = item & 255;  // 64-row tile
  const int e = seg >> 2;
  const long long arow0 = (long long)seg * 1024 + tile * 64;
  __shared__ __attribute__((aligned(16))) u16 As[64 * BK];
  __shared__ __attribute__((aligned(16))) u16 Bs[128 * BK];
  constexpr int LPR = BK / 8;        // lanes per row in a staging instruction
  constexpr int RPI = 512 / BK;      // rows per staging instruction
  constexpr int AIPW = BK / 32;      // A staging instructions per wave
  constexpr int BIPW = BK / 16;      // B staging instructions per wave
  const int tid = threadIdx.x, wave = tid >> 6, lane = tid & 63;
  const int lrow = lane / LPR, lpos = lane % LPR;
  const int lm = lane & 15, quad = lane >> 4;
  const long long bn = (long long)blockIdx.y * 128;
  const u16* Bg = Bw + ((long long)e * Bstride + bn) * K;
  int tok[AIPW];
  if (GATHER) {
#pragma unroll
    for (int i = 0; i < AIPW; ++i) tok[i] = tlist[arow0 + (wave * AIPW + i) * RPI + lrow];
  }
  f32x4 acc[4][2] = {};
  for (int kk = 0; kk < K; kk += BK) {
    __syncthreads();
#pragma unroll
    for (int i = 0; i < AIPW; ++i) {
      const int gi = wave * AIPW + i;
      const int row = gi * RPI + lrow;        // 0..63
      const int sc = lpos ^ (row & 7);
      if (GATHER)
        async16(A + (long long)tok[i] * K + kk + sc * 8, &As[gi * 512]);
      else
        async16(A + (arow0 + row) * K + kk + sc * 8, &As[gi * 512]);
    }
#pragma unroll
    for (int i = 0; i < BIPW; ++i) {
      const int gi = wave * BIPW + i;
      const int row = gi * RPI + lrow;        // 0..127
      const int sc = lpos ^ (row & 7);
      async16(Bg + (long long)row * K + kk + sc * 8, &Bs[gi * 512]);
    }
    __syncthreads();
#pragma unroll
    for (int ks = 0; ks < BK / 32; ++ks) {
      bf16x8 af[4], bfr[2];
#pragma unroll
      for (int mi = 0; mi < 4; ++mi) {
        const int row = mi * 16 + lm;
        const int ch = (ks * 4 + quad) ^ (row & 7);
        af[mi] = *(const bf16x8*)(As + row * BK + ch * 8);
      }
#pragma unroll
      for (int nj = 0; nj < 2; ++nj) {
        const int row = wave * 32 + nj * 16 + lm;
        const int ch = (ks * 4 + quad) ^ (row & 7);
        bfr[nj] = *(const bf16x8*)(Bs + row * BK + ch * 8);
      }
#pragma unroll
      for (int mi = 0; mi < 4; ++mi)
#pragma unroll
        for (int nj = 0; nj < 2; ++nj)
          acc[mi][nj] = __builtin_amdgcn_mfma_f32_16x16x32_bf16(bfr[nj], af[mi], acc[mi][nj], 0, 0, 0);
    }
  }
  const float* bs = bias + (long long)e * Bstride;
#pragma unroll
  for (int mi = 0; mi < 4; ++mi) {
    const long long p = arow0 + mi * 16 + lm;  // compact output row
#pragma unroll
    for (int nj = 0; nj < 2; ++nj) {
      const int n0 = (int)bn + wave * 32 + nj * 16 + quad * 4;
      const float4 bv = *(const float4*)(bs + n0);
      float v0 = acc[mi][nj][0] + bv.x;
      float v1 = acc[mi][nj][1] + bv.y;
      float v2 = acc[mi][nj][2] + bv.z;
      float v3 = acc[mi][nj][3] + bv.w;
      if (GELU) { v0 = gelu_f(v0); v1 = gelu_f(v1); v2 = gelu_f(v2); v3 = gelu_f(v3); }
      uint2 pk; pk.x = pack2bf(v0, v1); pk.y = pack2bf(v2, v3);
      *(uint2*)(Cout + p * N + n0) = pk;
    }
  }
}

// -------- flash attention: ONE block per (128-row q-pair, head). 1D grid with head in --------
// the LOW 3 bits of blockIdx.x: linear-id mod 8 = head -> all blocks of head h land on
// XCD h (round-robin dispatch), so K/V chunk re-reads across q-tiles of a segment hit
// that XCD's L2 instead of being duplicated across 8 XCDs.
__global__ __launch_bounds__(256, 4) void attn_tile(const u16* __restrict__ qb,
                                                    const u16* __restrict__ kb,
                                                    const u16* __restrict__ vT,
                                                    u16* __restrict__ ctx,
                                                    const int* __restrict__ wl) {
  const int idx = blockIdx.x >> 3, h = blockIdx.x & 7;
  if (idx >= wl[96]) return;
  const int item = wl[idx];
  const int seg = item >> 8, tile = item & 255;
  const int e = seg >> 2, b = seg & 3;
  __shared__ __attribute__((aligned(16))) u16 Ks[64 * 64];     // [key][d] swizzled
  __shared__ __attribute__((aligned(16))) u16 Vs[64 * 64];     // [d][key] swizzled
  __shared__ __attribute__((aligned(16))) u16 Pl[4][16 * 72];  // per-wave P[q][key], stride 72
  const int tid = threadIdx.x, wave = tid >> 6, lane = tid & 63;
  const int lm = lane & 15, quad = lane >> 4;
  const u16* kbase = kb + ((long long)e * Mc + b * Sc) * 512;
  const u16* vbase = vT + ((((long long)e * Bc + b) * Hc + h) * 64) * Sc;
  const int lr = lane >> 3, lc = (lane & 7) ^ lr;
  u16* P = &Pl[wave][0];
  unsigned* P32 = (unsigned*)P;
  const int pwbase = lm * 36 + quad * 2;  // dword index of this lane's P writes

  // q fragments for this lane's rows in both 64-row sub-tiles (compact layout)
  const long long pidx0 = (long long)seg * 1024 + tile * 128 + wave * 16 + lm;
  bf16x8 aq[2][2];
#pragma unroll
  for (int t = 0; t < 2; ++t)
#pragma unroll
    for (int ks = 0; ks < 2; ++ks)
      aq[t][ks] = *(const bf16x8*)(qb + (pidx0 + t * 64) * 512 + h * 64 + ks * 32 + quad * 8);
  f32x4 O[2][4] = {};
  float lsum[2] = {0.f, 0.f};

  for (int n0 = 0; n0 < Sc; n0 += 64) {
    __syncthreads();
#pragma unroll
    for (int i = 0; i < 2; ++i) {
      const int rg = wave * 2 + i;  // 0..7
      const int row = rg * 8 + lr;  // 0..63
      async16(kbase + (long long)(n0 + row) * 512 + h * 64 + lc * 8, &Ks[rg * 512]);
      async16(vbase + (long long)row * Sc + n0 + lc * 8, &Vs[rg * 512]);
    }
    __syncthreads();
    // hoist K fragments (shared by both q sub-tiles)
    bf16x8 kf[4][2];
#pragma unroll
    for (int kj = 0; kj < 4; ++kj) {
      const int row = kj * 16 + lm;
      kf[kj][0] = *(const bf16x8*)(Ks + row * 64 + ((quad) ^ (row & 7)) * 8);
      kf[kj][1] = *(const bf16x8*)(Ks + row * 64 + ((4 + quad) ^ (row & 7)) * 8);
    }
    bf16x8 ap[2][2];
#pragma unroll
    for (int t = 0; t < 2; ++t) {
      // S^T = K @ Q^T : C-layout row = key = kj*16 + quad*4 + r, col = q = lm
      f32x4 sT[4];
#pragma unroll
      for (int kj = 0; kj < 4; ++kj) {
        f32x4 c = {};
        c = __builtin_amdgcn_mfma_f32_16x16x32_bf16(kf[kj][0], aq[t][0], c, 0, 0, 0);
        c = __builtin_amdgcn_mfma_f32_16x16x32_bf16(kf[kj][1], aq[t][1], c, 0, 0, 0);
        sT[kj] = c;
      }
      // p = exp(s/8) (scores bounded -> no running-max rescale); local denom
#pragma unroll
      for (int kj = 0; kj < 4; ++kj) {
        const float p0 = __expf(sT[kj][0] * 0.125f);
        const float p1 = __expf(sT[kj][1] * 0.125f);
        const float p2 = __expf(sT[kj][2] * 0.125f);
        const float p3 = __expf(sT[kj][3] * 0.125f);
        lsum[t] += (p0 + p1) + (p2 + p3);
        P32[pwbase + kj * 8 + 0] = pack2bf(p0, p1);
        P32[pwbase + kj * 8 + 1] = pack2bf(p2, p3);
      }
      asm volatile("s_waitcnt lgkmcnt(0)" ::: "memory");
      ap[t][0] = *(const bf16x8*)(P + lm * 72 + quad * 8);
      ap[t][1] = *(const bf16x8*)(P + lm * 72 + 32 + quad * 8);
    }
    // PV with hoisted V fragments: O^T[d][q] += V^T[d][key] * P[q][key]
#pragma unroll
    for (int d4 = 0; d4 < 4; ++d4) {
      const int row = d4 * 16 + lm;
      const bf16x8 v0 = *(const bf16x8*)(Vs + row * 64 + ((quad) ^ (row & 7)) * 8);
      const bf16x8 v1 = *(const bf16x8*)(Vs + row * 64 + ((4 + quad) ^ (row & 7)) * 8);
#pragma unroll
      for (int t = 0; t < 2; ++t) {
        O[t][d4] = __builtin_amdgcn_mfma_f32_16x16x32_bf16(v0, ap[t][0], O[t][d4], 0, 0, 0);
        O[t][d4] = __builtin_amdgcn_mfma_f32_16x16x32_bf16(v1, ap[t][1], O[t][d4], 0, 0, 0);
      }
    }
  }
#pragma unroll
  for (int t = 0; t < 2; ++t) {
    float ls = lsum[t];
    ls += __shfl_xor(ls, 16);
    ls += __shfl_xor(ls, 32);
    const float inv = 1.0f / ls;  // per-lane correct for q = lm
#pragma unroll
    for (int d4 = 0; d4 < 4; ++d4) {
      uint2 pk;
      pk.x = pack2bf(O[t][d4][0] * inv, O[t][d4][1] * inv);
      pk.y = pack2bf(O[t][d4][2] * inv, O[t][d4][3] * inv);
      *(uint2*)(ctx + (pidx0 + t * 64) * 512 + h * 64 + d4 * 16 + quad * 4) = pk;
    }
  }
}

// ---------------- LN1 (routed): x1[p] = LN(x[tlist[p]] + ctxp[p]; g1,be1) -> bf16 ----------------
__global__ __launch_bounds__(256) void ln1_kernel(const float* __restrict__ x,
                                                  const u16* __restrict__ ctxp,
                                                  const float* __restrict__ g1,
                                                  const float* __restrict__ be1,
                                                  u16* __restrict__ x1,
                                                  const int* __restrict__ cnt,
                                                  const int* __restrict__ tlist) {
  const int i = blockIdx.x, b = blockIdx.y, e = blockIdx.z;
  const int seg = (e << 2) + b;
  const int ce = (cnt[seg] + 127) & ~127;
  if (i >= ce) return;  // compute all padded rows so downstream GEMM reads defined data
  const long long p = seg * 1024 + i;
  const int t = tlist[p];
  const int tid = threadIdx.x;
  const int wave = tid >> 6, lane = tid & 63;
  __shared__ float sred[4], qred[4];
  const float v0 = x[(long long)t * 512 + tid] + bf2f(ctxp[p * 512 + tid]);
  const float v1 = x[(long long)t * 512 + tid + 256] + bf2f(ctxp[p * 512 + tid + 256]);
  float s = v0 + v1, q = v0 * v0 + v1 * v1;
#pragma unroll
  for (int off = 32; off; off >>= 1) { s += __shfl_xor(s, off); q += __shfl_xor(q, off); }
  if (lane == 0) { sred[wave] = s; qred[wave] = q; }
  __syncthreads();
  s = sred[0] + sred[1] + sred[2] + sred[3];
  q = qred[0] + qred[1] + qred[2] + qred[3];
  const float mean = s * (1.0f / 512.0f);
  const float var = q * (1.0f / 512.0f) - mean * mean;
  const float rstd = rsqrtf(var + 1e-5f);
  x1[p * 512 + tid] = f2bf((v0 - mean) * rstd * g1[e * 512 + tid] + be1[e * 512 + tid]);
  x1[p * 512 + tid + 256] =
      f2bf((v1 - mean) * rstd * g1[e * 512 + tid + 256] + be1[e * 512 + tid + 256]);
}

// ---------------- LN2 + gate-weighted combine: out[t] = sum_e w[t,e]*LN(x1[p]+h2[p]) ----------------
__global__ __launch_bounds__(256) void ln2_kernel(const u16* __restrict__ x1,
                                                  const u16* __restrict__ h2,
                                                  const float* __restrict__ g2,
                                                  const float* __restrict__ be2,
                                                  const float* __restrict__ gated,
                                                  const int* __restrict__ pos,
                                                  float* __restrict__ out) {
  const int t = blockIdx.x, tid = threadIdx.x;
  const int b = t >> 10;
  const int wave = tid >> 6, lane = tid & 63;
  __shared__ float sred[4], qred[4];
  float o0 = 0.f, o1 = 0.f;
  for (int e = 0; e < 8; ++e) {
    const float wgt = gated[t * 8 + e];
    if (wgt != 0.f) {  // block-uniform branch (depends on t only)
      const long long p = ((e << 2) + b) * 1024 + pos[e * 4096 + t];
      const float v0 = bf2f(x1[p * 512 + tid]) + bf2f(h2[p * 512 + tid]);
      const float v1 = bf2f(x1[p * 512 + tid + 256]) + bf2f(h2[p * 512 + tid + 256]);
      float s = v0 + v1, q = v0 * v0 + v1 * v1;
#pragma unroll
      for (int off = 32; off; off >>= 1) { s += __shfl_xor(s, off); q += __shfl_xor(q, off); }
      if (lane == 0) { sred[wave] = s; qred[wave] = q; }
      __syncthreads();
      s = sred[0] + sred[1] + sred[2] + sred[3];
      q = qred[0] + qred[1] + qred[2] + qred[3];
      __syncthreads();
      const float mean = s * (1.0f / 512.0f);
      const float var = q * (1.0f / 512.0f) - mean * mean;
      const float rstd = rsqrtf(var + 1e-5f);
      o0 += wgt * ((v0 - mean) * rstd * g2[e * 512 + tid] + be2[e * 512 + tid]);
      o1 += wgt * ((v1 - mean) * rstd * g2[e * 512 + tid + 256] + be2[e * 512 + tid + 256]);
    }
  }
  out[(long long)t * 512 + tid] = o0;
  out[(long long)t * 512 + tid + 256] = o1;
}

// ---------------- launch ----------------
extern "C" void kernel_launch(void* const* d_in, const int* in_sizes, int n_in, void* d_out,
                              int out_size, void* d_ws, size_t ws_size, hipStream_t stream) {
  const float* x    = (const float*)d_in[0];
  const float* gWk  = (const float*)d_in[1];
  const float* gbk  = (const float*)d_in[2];
  const float* eq   = (const float*)d_in[3];
  const float* Wqkv = (const float*)d_in[4];
  const float* bqkv = (const float*)d_in[5];
  const float* Wo   = (const float*)d_in[6];
  const float* bo   = (const float*)d_in[7];
  const float* g1   = (const float*)d_in[8];
  const float* be1  = (const float*)d_in[9];
  const float* W1   = (const float*)d_in[10];
  const float* bf1  = (const float*)d_in[11];
  const float* W2   = (const float*)d_in[12];
  const float* bf2  = (const float*)d_in[13];
  const float* g2   = (const float*)d_in[14];
  const float* be2  = (const float*)d_in[15];
  float* out = (float*)d_out;

  char* wsp = (char*)d_ws;
  size_t off = 0;
  auto take = [&](size_t bytes) -> void* {
    void* p = wsp + off;
    off += (bytes + 255) & ~(size_t)255;
    return p;
  };
  u16* xb    = (u16*)take((size_t)Mc * 512 * 2);
  u16* Wqkvb = (u16*)take((size_t)Ec * 1536 * 512 * 2);
  u16* Wob   = (u16*)take((size_t)Ec * 512 * 512 * 2);
  u16* W1b   = (u16*)take((size_t)Ec * 2048 * 512 * 2);
  u16* W2b   = (u16*)take((size_t)Ec * 512 * 2048 * 2);
  float* weq   = (float*)take(8 * 512 * 4);
  float* beqb  = (float*)take(8 * 4);
  float* gated = (float*)take((size_t)Mc * 8 * 4);
  int* emask = (int*)take((size_t)Mc * 4);
  int* cnt   = (int*)take(32 * 4);
  int* tlist = (int*)take(32 * 1024 * 4);
  int* pos   = (int*)take((size_t)Ec * Mc * 4);
  int* wl    = (int*)take(1024 * 4);
  char* big = (char*)take(134217728);
  u16* qb   = (u16*)big;                  // compact q [32768][512], dead after attn
  u16* kb   = (u16*)(big + 33554432);     // k [E][M][512], dead after attn
  u16* vTb  = (u16*)(big + 67108864);     // [E][B][H][64][S], dead after attn
  u16* ctxp = (u16*)(big + 100663296);    // compact [32768][512], dead after ln1
  u16* hb   = (u16*)big;                  // compact [32768][2048], written after ln1
  u16* ctxb = (u16*)take(33554432);       // compact attn out, dead after Wo GEMM
  u16* h2b  = ctxb;                       // compact W2 out, written after W1
  u16* x1b  = (u16*)take(33554432);       // compact [32768][512]
  (void)in_sizes; (void)n_in; (void)out_size; (void)ws_size;

  // fp32 -> bf16 converts (single fused launch)
  cvt5_kernel<<<dim3(26624), dim3(256), 0, stream>>>(x, xb, Wqkv, Wqkvb, Wo, Wob, W1, W1b, W2, W2b);
  // gating (fp32 path; keys GEMM folded into weq precompute, beq folded into weq launch);
  // atomic-free two-pass routing
  weq_kernel<<<dim3(8, 8), dim3(256), 0, stream>>>(gWk, eq, gbk, weq, beqb);
  gate_kernel<<<dim3(1024), dim3(256), 0, stream>>>(x, weq, beqb, gated, emask);
  build_kernel<<<dim3(32), dim3(256), 0, stream>>>(emask, cnt, tlist, pos);
  wl_kernel<<<dim3(1), dim3(64), 0, stream>>>(cnt, wl);
  // k+v dense MERGED, counted-vmcnt dbuf pipeline.
  // grid (32,8,8); y<4 -> k into kb, y>=4 -> v (swapped ops) into vT.
  gemm_bf16<0, 2, 0, 64><<<dim3(32, 8, 8), dim3(256), 0, stream>>>(
      xb, Wqkvb + 512 * 512, bqkv + 512, kb, vTb, Mc, 1024, 512, 0LL, 1536LL, wl);
  // q routed: 64-row tiles (BK=128), A rows gathered through tlist, compact output
  gemm64_bf16<0, 1, 128><<<dim3(192, 4), dim3(256), 0, stream>>>(
      xb, Wqkvb, bqkv, qb, 512, 512, 1536LL, wl, tlist);
  // attention: 1D grid, head in low 3 bits (head -> XCD pinning for K/V L2 reuse)
  attn_tile<<<dim3(96 * 8), dim3(256), 0, stream>>>(qb, kb, vTb, ctxb, wl);
  // Wo routed: 64-row tiles (BK=128)
  gemm64_bf16<0, 0, 128><<<dim3(192, 4), dim3(256), 0, stream>>>(
      ctxb, Wob, bo, ctxp, 512, 512, 512LL, wl, nullptr);
  ln1_kernel<<<dim3(1024, 4, 8), dim3(256), 0, stream>>>(x, ctxp, g1, be1, x1b, cnt, tlist);
  // W1 routed: expert->XCD-pinned grid (blockIdx.x = expert = linear id % 8), BK=64,
  // counted-vmcnt dbuf pipeline.
  gemm_bf16<1, 0, 3, 64><<<dim3(8, 32, 16), dim3(256), 0, stream>>>(
      x1b, W1b, bf1, hb, nullptr, Mc, 2048, 512, (long long)Mc * 512, 2048LL, wl);
  // W2 routed: 64-row tiles (BK=128), K=2048
  gemm64_bf16<1, 0, 128><<<dim3(192, 4), dim3(256), 0, stream>>>(
      hb, W2b, bf2, h2b, 512, 2048, 512LL, wl, nullptr);
  ln2_kernel<<<dim3(4096), dim3(256), 0, stream>>>(x1b, h2b, g2, be2, gated, pos, out);
}

// Round 16
// 425.133 us; speedup vs baseline: 1.0288x; 1.0288x over previous
//
#include <hip/hip_runtime.h>
#include <cstdint>
#include <cmath>

// Problem constants (B,S,D,F,E,K,H = 4,1024,512,2048,8,2,8; HEAD_DIM=64)
#define Bc 4
#define Sc 1024
#define Dc 512
#define Fc 2048
#define Ec 8
#define Hc 8
#define Mc 4096  // B*S

typedef unsigned short u16;
typedef __attribute__((ext_vector_type(8))) short bf16x8;  // 8 bf16 = 4 VGPRs
typedef __attribute__((ext_vector_type(4))) float f32x4;

__device__ __forceinline__ float bf2f(u16 u) {
  unsigned v = ((unsigned)u) << 16;
  return __builtin_bit_cast(float, v);
}
__device__ __forceinline__ u16 f2bf(float f) {
  unsigned u = __builtin_bit_cast(unsigned, f);
  unsigned r = 0x7fffu + ((u >> 16) & 1u);
  return (u16)((u + r) >> 16);
}
__device__ __forceinline__ unsigned pack2bf(float a, float b) {
  return (unsigned)f2bf(a) | ((unsigned)f2bf(b) << 16);
}
// tanh-approx GELU (max abs err ~3e-4 vs exact erf-GELU; threshold headroom is ~0.07)
__device__ __forceinline__ float gelu_f(float x) {
  const float z = 1.5957691216057308f * fmaf(0.044715f * x, x * x, x);  // 2*sqrt(2/pi)*(x+c x^3)
  const float e = __expf(z);
  return x * (1.0f - __builtin_amdgcn_rcpf(e + 1.0f));
}
// async global->LDS, 16B per lane; LDS dest = base + lane*16 (wave-uniform base)
__device__ __forceinline__ void async16(const void* g, void* l) {
  __builtin_amdgcn_global_load_lds(
      (const __attribute__((address_space(1))) unsigned int*)g,
      (__attribute__((address_space(3))) unsigned int*)l, 16, 0, 0);
}

// fused f32 -> bf16 conversion for all 5 input tensors (single launch; each block does 1024 elems)
__global__ __launch_bounds__(256) void cvt5_kernel(const float* __restrict__ p0, u16* __restrict__ q0,
                                                   const float* __restrict__ p1, u16* __restrict__ q1,
                                                   const float* __restrict__ p2, u16* __restrict__ q2,
                                                   const float* __restrict__ p3, u16* __restrict__ q3,
                                                   const float* __restrict__ p4, u16* __restrict__ q4) {
  int bx = blockIdx.x;
  const float* in;
  u16* outp;
  if (bx < 2048) { in = p0; outp = q0; }                       // x: 2,097,152
  else if (bx < 8192) { in = p1; outp = q1; bx -= 2048; }      // Wqkv: 6,291,456
  else if (bx < 10240) { in = p2; outp = q2; bx -= 8192; }     // Wo: 2,097,152
  else if (bx < 18432) { in = p3; outp = q3; bx -= 10240; }    // W1: 8,388,608
  else { in = p4; outp = q4; bx -= 18432; }                    // W2: 8,388,608
  const long long i = ((long long)bx * 256 + threadIdx.x) * 4;
  const float4 v = *(const float4*)(in + i);
  ushort4 o;
  o.x = f2bf(v.x); o.y = f2bf(v.y); o.z = f2bf(v.z); o.w = f2bf(v.w);
  *(ushort4*)(outp + i) = o;
}

// ---------------- gating precompute: weq[e][d] = sum_j eq[e][j] * gWk[j][d] ----------------
// Block (0, e) additionally computes beq[e] = <gbk, eq[e]> (folds the old beq_kernel launch).
__global__ __launch_bounds__(256) void weq_kernel(const float* __restrict__ gWk,
                                                  const float* __restrict__ eq,
                                                  const float* __restrict__ gbk,
                                                  float* __restrict__ weq,
                                                  float* __restrict__ beq) {
  __shared__ float red[4][64];
  const int tid = threadIdx.x, wave = tid >> 6, lane = tid & 63;
  const int d = blockIdx.x * 64 + lane;
  const int e = blockIdx.y;
  float acc = 0.f;
  for (int j = wave * 128; j < wave * 128 + 128; ++j)
    acc += gWk[(long long)j * 512 + d] * eq[e * 512 + j];
  red[wave][lane] = acc;
  __syncthreads();
  if (wave == 0)
    weq[e * 512 + d] = red[0][lane] + red[1][lane] + red[2][lane] + red[3][lane];
  if (blockIdx.x == 0 && wave == 1) {
    float a = 0.f;
#pragma unroll
    for (int i = 0; i < 8; ++i) a += gbk[lane + 64 * i] * eq[e * 512 + lane + 64 * i];
#pragma unroll
    for (int off = 32; off; off >>= 1) a += __shfl_xor(a, off);
    if (lane == 0) beq[e] = a;
  }
}

// ---- gating pass 1: scores = (x@weq^T + beq)*D^-0.5, softmax(E=8), top-2, renorm.   ----
// Writes gated[t][8] + emask[t] (bit e set if expert e selected). NO ATOMICS (R10: the
// old dependent atomicAdds on one 128B region serialized through one L2 slice, 54.8us).
__global__ __launch_bounds__(256) void gate_kernel(const float* __restrict__ x,
                                                   const float* __restrict__ weq,
                                                   const float* __restrict__ beq,
                                                   float* __restrict__ gated,
                                                   int* __restrict__ emask) {
  const int wave = threadIdx.x >> 6, lane = threadIdx.x & 63;
  const int t = blockIdx.x * 4 + wave;
  const float* xr = x + (long long)t * 512;
  float acc[8] = {};
#pragma unroll
  for (int i = 0; i < 8; ++i) {
    const float xv = xr[lane + 64 * i];
#pragma unroll
    for (int e2 = 0; e2 < 8; ++e2) acc[e2] += xv * weq[e2 * 512 + lane + 64 * i];
  }
#pragma unroll
  for (int e2 = 0; e2 < 8; ++e2)
#pragma unroll
    for (int off = 32; off; off >>= 1) acc[e2] += __shfl_xor(acc[e2], off);
  if (lane == 0) {
    const float scale = 0.044194173824159216f;  // 512^-0.5
    float s[8], mx = -1e30f;
#pragma unroll
    for (int e2 = 0; e2 < 8; ++e2) { s[e2] = (acc[e2] + beq[e2]) * scale; mx = fmaxf(mx, s[e2]); }
    float p[8], sum = 0.f;
#pragma unroll
    for (int e2 = 0; e2 < 8; ++e2) { p[e2] = expf(s[e2] - mx); sum += p[e2]; }
#pragma unroll
    for (int e2 = 0; e2 < 8; ++e2) p[e2] /= sum;
    int i1 = 0;
#pragma unroll
    for (int e2 = 1; e2 < 8; ++e2) if (p[e2] > p[i1]) i1 = e2;
    int i2 = (i1 == 0) ? 1 : 0;
#pragma unroll
    for (int e2 = 0; e2 < 8; ++e2) if (e2 != i1 && e2 != i2 && p[e2] > p[i2]) i2 = e2;
    const float denom = p[i1] + p[i2] + 1e-9f;
#pragma unroll
    for (int e2 = 0; e2 < 8; ++e2)
      gated[t * 8 + e2] = (e2 == i1 || e2 == i2) ? p[e2] / denom : 0.f;
    emask[t] = (1 << i1) | (1 << i2);
  }
}

// ---- gating pass 2: deterministic routing-list build. One block per (e,b) segment;   ----
// ballot-based prefix sum over the segment's 1024 tokens (token order) -> tlist/pos/cnt,
// then pad tlist to a multiple of 128 with a valid token (row 0 of sequence b).
__global__ __launch_bounds__(256) void build_kernel(const int* __restrict__ emask,
                                                    int* __restrict__ cnt,
                                                    int* __restrict__ tlist,
                                                    int* __restrict__ pos) {
  const int seg = blockIdx.x;  // e*4 + b
  const int e = seg >> 2, b = seg & 3;
  const int tid = threadIdx.x, wave = tid >> 6, lane = tid & 63;
  __shared__ int wbase[4];
  __shared__ int running;
  if (tid == 0) running = 0;
  __syncthreads();
  for (int i0 = 0; i0 < 1024; i0 += 256) {
    const int t = (b << 10) + i0 + tid;
    const int flag = (emask[t] >> e) & 1;
    const unsigned long long m = __ballot(flag);
    const int prefix = __popcll(m & ((1ULL << lane) - 1ULL));
    if (lane == 0) wbase[wave] = __popcll(m);
    __syncthreads();
    int base = running;
    for (int w = 0; w < wave; ++w) base += wbase[w];
    if (flag) {
      const int p = base + prefix;
      tlist[seg * 1024 + p] = t;
      pos[e * 4096 + t] = p;
    }
    __syncthreads();
    if (tid == 0) running += wbase[0] + wbase[1] + wbase[2] + wbase[3];
    __syncthreads();
  }
  const int c = running;  // final (all threads see it after the last barrier)
  if (tid == 0) cnt[seg] = c;
  const int ce = (c + 127) & ~127;
  const int tpad = b << 10;
  for (int i = c + tid; i < ce; i += 256) tlist[seg * 1024 + i] = tpad;
}

// ---- work lists (all compacted so active blocks are contiguous in linear block id):  ----
// wl[0..95]   : 128-row tiles (seg<<8|tile), total at wl[96]
// wl[97]      : total 64-row tiles; wl[128..319]: 64-row tiles (seg<<8|tile)
// wl[104+e]   : per-expert 128-row tile count; wl[320+e*32+j]: expert e's tiles
__global__ void wl_kernel(const int* __restrict__ cnt, int* __restrict__ wl) {
  const int tid = threadIdx.x;
  if (tid < 32) {
    const int seg = tid;
    int base = 0;
    for (int s = 0; s < seg; ++s) base += (cnt[s] + 127) >> 7;
    const int nt = (cnt[seg] + 127) >> 7;
    for (int t = 0; t < nt; ++t) wl[base + t] = (seg << 8) | t;
    for (int t = 0; t < 2 * nt; ++t) wl[128 + 2 * base + t] = (seg << 8) | t;
    if (seg == 31) { wl[96] = base + nt; wl[97] = 2 * (base + nt); }
  } else if (tid < 40) {
    const int e = tid - 32;
    int n = 0;
    for (int b = 0; b < 4; ++b) {
      const int seg = e * 4 + b;
      const int nt = (cnt[seg] + 127) >> 7;
      for (int t = 0; t < nt; ++t) wl[320 + e * 32 + n++] = (seg << 8) | t;
    }
    wl[104 + e] = n;
  }
}

// ---------------- bf16 MFMA GEMM: C[m,n] = sum_k A[m,k]*Bt[n,k] + bias[n] ----------------
// 128x128 tile, 4 waves each 64x64 (4x4 of 16x16x32 MFMA).
// DBUF=1: 2-phase LDS double-buffer (64 KB). Measured: KV merged 61us dbuf vs 71us single
//   (R12/R13) and W1 53us dbuf -- intra-block overlap is the reliable latency cover here.
//   (R15: T4 counted-vmcnt graft on this 2-phase loop = null, consistent with m230/m248 --
//    counted vmcnt pays only inside the full 8-phase interleave.)
// EPI=2: merged KV launch, grid (32,8,8): bn<512 -> k path (generic epilogue into kb),
//   bn>=512 -> v path (swapped MFMA operands -> coalesced transposed-vT stores).
// ROUTED=1: (expert,bseg,tile) from wl[0..], n-panel from blockIdx.y.
// ROUTED=3: expert->XCD-pinned grid dim3(8, 32, N/128): blockIdx.x = expert (linear id
//   % 8 = x -> all blocks of expert e on XCD e; W1_e + A_e L2-resident: FETCH 81->17 MB).
template <int GELU, int EPI, int ROUTED, int BK, int DBUF>
__global__ __launch_bounds__(256) void gemm_bf16(
    const u16* __restrict__ A, const u16* __restrict__ Bw, const float* __restrict__ bias,
    u16* __restrict__ Cout, u16* __restrict__ vT, int M, int N, int K, long long Astride,
    long long Bstride, const int* __restrict__ wl) {
  int e;
  long long bm, bn;
  if (ROUTED == 1) {
    const int total = wl[96];
    if ((int)blockIdx.x >= total) return;
    const int item = wl[blockIdx.x];
    const int seg = item >> 8, tile = item & 255;
    e = seg >> 2;
    bm = ((long long)(seg & 3) << 10) + tile * 128;
    bn = (long long)blockIdx.y * 128;
  } else if (ROUTED == 3) {
    e = blockIdx.x;  // 0..7, linear id % 8 == e (gridDim.x == 8)
    if ((int)blockIdx.y >= wl[104 + e]) return;
    const int item = wl[320 + e * 32 + blockIdx.y];
    const int seg = item >> 8, tile = item & 255;
    bm = ((long long)(seg & 3) << 10) + tile * 128;
    bn = (long long)blockIdx.z * 128;
  } else {
    e = blockIdx.z;
    bm = (long long)blockIdx.x * 128;
    bn = (long long)blockIdx.y * 128;
  }
  __shared__ __attribute__((aligned(16))) u16 As[DBUF ? 2 : 1][128 * BK];
  __shared__ __attribute__((aligned(16))) u16 Bs[DBUF ? 2 : 1][128 * BK];
  const int tid = threadIdx.x;
  const int wave = tid >> 6, lane = tid & 63;
  const u16* Ag = A + (long long)e * Astride + bm * K;
  const u16* Bg = Bw + ((long long)e * Bstride + bn) * K;
  constexpr int LPR = BK / 8;   // lanes per row in a staging instruction
  constexpr int RPI = 512 / BK; // rows per staging instruction
  constexpr int IPW = BK / 16;  // staging instructions per wave (each of A and B)
  const int lrow = lane / LPR, lpos = lane % LPR;
  const int lm = lane & 15, quad = lane >> 4;
  const int wm = (wave >> 1) * 64, wn = (wave & 1) * 64;
  const bool isv = (EPI == 2) && (bn >= 512);
  f32x4 acc[4][4] = {};

  auto stage = [&](int buf, int kk) {
#pragma unroll
    for (int i = 0; i < IPW; ++i) {
      const int gi = wave * IPW + i;        // instruction slot 0..BK/4-1
      const int row = gi * RPI + lrow;      // tile row 0..127
      const int sc = lpos ^ (row & 7);      // XOR-swizzled source chunk
      async16(Ag + (long long)row * K + kk + sc * 8, &As[buf][gi * 512]);
      async16(Bg + (long long)row * K + kk + sc * 8, &Bs[buf][gi * 512]);
    }
  };
  auto computeN = [&](int buf) {  // normal operand order: lane owns output rows
#pragma unroll
    for (int ks = 0; ks < BK / 32; ++ks) {
      bf16x8 af[4], bfr[4];
#pragma unroll
      for (int mi = 0; mi < 4; ++mi) {
        const int row = wm + mi * 16 + lm;
        const int ch = (ks * 4 + quad) ^ (row & 7);
        af[mi] = *(const bf16x8*)(&As[buf][row * BK + ch * 8]);
      }
#pragma unroll
      for (int nj = 0; nj < 4; ++nj) {
        const int row = wn + nj * 16 + lm;
        const int ch = (ks * 4 + quad) ^ (row & 7);
        bfr[nj] = *(const bf16x8*)(&Bs[buf][row * BK + ch * 8]);
      }
#pragma unroll
      for (int mi = 0; mi < 4; ++mi)
#pragma unroll
        for (int nj = 0; nj < 4; ++nj)
          acc[mi][nj] = __builtin_amdgcn_mfma_f32_16x16x32_bf16(bfr[nj], af[mi], acc[mi][nj], 0, 0, 0);
    }
  };
  auto computeV = [&](int buf) {  // swapped operand order: lane owns output cols
#pragma unroll
    for (int ks = 0; ks < BK / 32; ++ks) {
      bf16x8 af[4], bfr[4];
#pragma unroll
      for (int mi = 0; mi < 4; ++mi) {
        const int row = wm + mi * 16 + lm;
        const int ch = (ks * 4 + quad) ^ (row & 7);
        af[mi] = *(const bf16x8*)(&As[buf][row * BK + ch * 8]);
      }
#pragma unroll
      for (int nj = 0; nj < 4; ++nj) {
        const int row = wn + nj * 16 + lm;
        const int ch = (ks * 4 + quad) ^ (row & 7);
        bfr[nj] = *(const bf16x8*)(&Bs[buf][row * BK + ch * 8]);
      }
#pragma unroll
      for (int mi = 0; mi < 4; ++mi)
#pragma unroll
        for (int nj = 0; nj < 4; ++nj)
          acc[mi][nj] = __builtin_amdgcn_mfma_f32_16x16x32_bf16(af[mi], bfr[nj], acc[mi][nj], 0, 0, 0);
    }
  };

  if (DBUF) {
    // 2-phase double-buffered K-loop (K/BK even for all instantiations)
    stage(0, 0);
    __syncthreads();
    if (!isv) {
      for (int kk = 0; kk < K; kk += 2 * BK) {
        if (kk + BK < K) stage(1, kk + BK);
        computeN(0);
        __syncthreads();  // drains vmcnt (buf1 staged) + all waves done reading buf0
        if (kk + 2 * BK < K) stage(0, kk + 2 * BK);
        computeN(1);
        __syncthreads();
      }
    } else {
      for (int kk = 0; kk < K; kk += 2 * BK) {
        if (kk + BK < K) stage(1, kk + BK);
        computeV(0);
        __syncthreads();
        if (kk + 2 * BK < K) stage(0, kk + 2 * BK);
        computeV(1);
        __syncthreads();
      }
    }
  } else {
    for (int kk = 0; kk < K; kk += BK) {
      __syncthreads();
      stage(0, kk);
      __syncthreads();
      if (!isv) computeN(0); else computeV(0);
    }
  }

  const float* bs = bias + (long long)e * Bstride;
  if (isv) {
    // v epilogue: lane owns col n (v d-dim = n-512), 4 consecutive rows m0 (tokens)
#pragma unroll
    for (int nj = 0; nj < 4; ++nj) {
      const int n = (int)bn + wn + nj * 16 + lm;  // 512..1023
      const float bvs = bs[n];
      const int hh = (n - 512) >> 6, dd = (n - 512) & 63;
#pragma unroll
      for (int mi = 0; mi < 4; ++mi) {
        const int m0 = (int)bm + wm + mi * 16 + quad * 4;
        const int bb = m0 >> 10, ss = m0 & 1023;
        uint2 pk;
        pk.x = pack2bf(acc[mi][nj][0] + bvs, acc[mi][nj][1] + bvs);
        pk.y = pack2bf(acc[mi][nj][2] + bvs, acc[mi][nj][3] + bvs);
        *(uint2*)(vT + ((((long long)e * Bc + bb) * Hc + hh) * 64 + dd) * Sc + ss) = pk;
      }
    }
    return;
  }
  // generic epilogue (also the k path of EPI=2): lane owns row m, 4 consecutive cols n0
#pragma unroll
  for (int mi = 0; mi < 4; ++mi) {
    const int m = (int)bm + wm + mi * 16 + lm;
#pragma unroll
    for (int nj = 0; nj < 4; ++nj) {
      const int n0 = (int)bn + wn + nj * 16 + quad * 4;
      const float4 bv = *(const float4*)(bs + n0);
      float v0 = acc[mi][nj][0] + bv.x;
      float v1 = acc[mi][nj][1] + bv.y;
      float v2 = acc[mi][nj][2] + bv.z;
      float v3 = acc[mi][nj][3] + bv.w;
      if (GELU) { v0 = gelu_f(v0); v1 = gelu_f(v1); v2 = gelu_f(v2); v3 = gelu_f(v3); }
      uint2 pk; pk.x = pack2bf(v0, v1); pk.y = pack2bf(v2, v3);
      *(uint2*)(Cout + ((long long)e * M + m) * N + n0) = pk;
    }
  }
}

// ---------------- 64-row routed GEMM: 64x128 tile, BK param, 4 waves each 64x32 ----------------
// For the N=512 routed GEMMs (Q, Wo, W2).
// A is compact p-space (p = seg*1024 + row) or token-gathered via tlist (GATHER).
template <int GELU, int GATHER, int BK>
__global__ __launch_bounds__(256) void gemm64_bf16(
    const u16* __restrict__ A, const u16* __restrict__ Bw, const float* __restrict__ bias,
    u16* __restrict__ Cout, int N, int K, long long Bstride,
    const int* __restrict__ wl, const int* __restrict__ tlist) {
  if ((int)blockIdx.x >= wl[97]) return;
  const int item = wl[128 + blockIdx.x];
  const int seg = item >> 8, tile = item & 255;  // 64-row tile
  const int e = seg >> 2;
  const long long arow0 = (long long)seg * 1024 + tile * 64;
  __shared__ __attribute__((aligned(16))) u16 As[64 * BK];
  __shared__ __attribute__((aligned(16))) u16 Bs[128 * BK];
  constexpr int LPR = BK / 8;        // lanes per row in a staging instruction
  constexpr int RPI = 512 / BK;      // rows per staging instruction
  constexpr int AIPW = BK / 32;      // A staging instructions per wave
  constexpr int BIPW = BK / 16;      // B staging instructions per wave
  const int tid = threadIdx.x, wave = tid >> 6, lane = tid & 63;
  const int lrow = lane / LPR, lpos = lane % LPR;
  const int lm = lane & 15, quad = lane >> 4;
  const long long bn = (long long)blockIdx.y * 128;
  const u16* Bg = Bw + ((long long)e * Bstride + bn) * K;
  int tok[AIPW];
  if (GATHER) {
#pragma unroll
    for (int i = 0; i < AIPW; ++i) tok[i] = tlist[arow0 + (wave * AIPW + i) * RPI + lrow];
  }
  f32x4 acc[4][2] = {};
  for (int kk = 0; kk < K; kk += BK) {
    __syncthreads();
#pragma unroll
    for (int i = 0; i < AIPW; ++i) {
      const int gi = wave * AIPW + i;
      const int row = gi * RPI + lrow;        // 0..63
      const int sc = lpos ^ (row & 7);
      if (GATHER)
        async16(A + (long long)tok[i] * K + kk + sc * 8, &As[gi * 512]);
      else
        async16(A + (arow0 + row) * K + kk + sc * 8, &As[gi * 512]);
    }
#pragma unroll
    for (int i = 0; i < BIPW; ++i) {
      const int gi = wave * BIPW + i;
      const int row = gi * RPI + lrow;        // 0..127
      const int sc = lpos ^ (row & 7);
      async16(Bg + (long long)row * K + kk + sc * 8, &Bs[gi * 512]);
    }
    __syncthreads();
#pragma unroll
    for (int ks = 0; ks < BK / 32; ++ks) {
      bf16x8 af[4], bfr[2];
#pragma unroll
      for (int mi = 0; mi < 4; ++mi) {
        const int row = mi * 16 + lm;
        const int ch = (ks * 4 + quad) ^ (row & 7);
        af[mi] = *(const bf16x8*)(As + row * BK + ch * 8);
      }
#pragma unroll
      for (int nj = 0; nj < 2; ++nj) {
        const int row = wave * 32 + nj * 16 + lm;
        const int ch = (ks * 4 + quad) ^ (row & 7);
        bfr[nj] = *(const bf16x8*)(Bs + row * BK + ch * 8);
      }
#pragma unroll
      for (int mi = 0; mi < 4; ++mi)
#pragma unroll
        for (int nj = 0; nj < 2; ++nj)
          acc[mi][nj] = __builtin_amdgcn_mfma_f32_16x16x32_bf16(bfr[nj], af[mi], acc[mi][nj], 0, 0, 0);
    }
  }
  const float* bs = bias + (long long)e * Bstride;
#pragma unroll
  for (int mi = 0; mi < 4; ++mi) {
    const long long p = arow0 + mi * 16 + lm;  // compact output row
#pragma unroll
    for (int nj = 0; nj < 2; ++nj) {
      const int n0 = (int)bn + wave * 32 + nj * 16 + quad * 4;
      const float4 bv = *(const float4*)(bs + n0);
      float v0 = acc[mi][nj][0] + bv.x;
      float v1 = acc[mi][nj][1] + bv.y;
      float v2 = acc[mi][nj][2] + bv.z;
      float v3 = acc[mi][nj][3] + bv.w;
      if (GELU) { v0 = gelu_f(v0); v1 = gelu_f(v1); v2 = gelu_f(v2); v3 = gelu_f(v3); }
      uint2 pk; pk.x = pack2bf(v0, v1); pk.y = pack2bf(v2, v3);
      *(uint2*)(Cout + p * N + n0) = pk;
    }
  }
}

// -------- flash attention: ONE block per (128-row q-pair, head). 1D grid with head in --------
// the LOW 3 bits of blockIdx.x: linear-id mod 8 = head -> all blocks of head h land on
// XCD h (round-robin dispatch), so K/V chunk re-reads across q-tiles of a segment hit
// that XCD's L2 instead of being duplicated across 8 XCDs.
__global__ __launch_bounds__(256, 4) void attn_tile(const u16* __restrict__ qb,
                                                    const u16* __restrict__ kb,
                                                    const u16* __restrict__ vT,
                                                    u16* __restrict__ ctx,
                                                    const int* __restrict__ wl) {
  const int idx = blockIdx.x >> 3, h = blockIdx.x & 7;
  if (idx >= wl[96]) return;
  const int item = wl[idx];
  const int seg = item >> 8, tile = item & 255;
  const int e = seg >> 2, b = seg & 3;
  __shared__ __attribute__((aligned(16))) u16 Ks[64 * 64];     // [key][d] swizzled
  __shared__ __attribute__((aligned(16))) u16 Vs[64 * 64];     // [d][key] swizzled
  __shared__ __attribute__((aligned(16))) u16 Pl[4][16 * 72];  // per-wave P[q][key], stride 72
  const int tid = threadIdx.x, wave = tid >> 6, lane = tid & 63;
  const int lm = lane & 15, quad = lane >> 4;
  const u16* kbase = kb + ((long long)e * Mc + b * Sc) * 512;
  const u16* vbase = vT + ((((long long)e * Bc + b) * Hc + h) * 64) * Sc;
  const int lr = lane >> 3, lc = (lane & 7) ^ lr;
  u16* P = &Pl[wave][0];
  unsigned* P32 = (unsigned*)P;
  const int pwbase = lm * 36 + quad * 2;  // dword index of this lane's P writes

  // q fragments for this lane's rows in both 64-row sub-tiles (compact layout)
  const long long pidx0 = (long long)seg * 1024 + tile * 128 + wave * 16 + lm;
  bf16x8 aq[2][2];
#pragma unroll
  for (int t = 0; t < 2; ++t)
#pragma unroll
    for (int ks = 0; ks < 2; ++ks)
      aq[t][ks] = *(const bf16x8*)(qb + (pidx0 + t * 64) * 512 + h * 64 + ks * 32 + quad * 8);
  f32x4 O[2][4] = {};
  float lsum[2] = {0.f, 0.f};

  for (int n0 = 0; n0 < Sc; n0 += 64) {
    __syncthreads();
#pragma unroll
    for (int i = 0; i < 2; ++i) {
      const int rg = wave * 2 + i;  // 0..7
      const int row = rg * 8 + lr;  // 0..63
      async16(kbase + (long long)(n0 + row) * 512 + h * 64 + lc * 8, &Ks[rg * 512]);
      async16(vbase + (long long)row * Sc + n0 + lc * 8, &Vs[rg * 512]);
    }
    __syncthreads();
    // hoist K fragments (shared by both q sub-tiles)
    bf16x8 kf[4][2];
#pragma unroll
    for (int kj = 0; kj < 4; ++kj) {
      const int row = kj * 16 + lm;
      kf[kj][0] = *(const bf16x8*)(Ks + row * 64 + ((quad) ^ (row & 7)) * 8);
      kf[kj][1] = *(const bf16x8*)(Ks + row * 64 + ((4 + quad) ^ (row & 7)) * 8);
    }
    bf16x8 ap[2][2];
#pragma unroll
    for (int t = 0; t < 2; ++t) {
      // S^T = K @ Q^T : C-layout row = key = kj*16 + quad*4 + r, col = q = lm
      f32x4 sT[4];
#pragma unroll
      for (int kj = 0; kj < 4; ++kj) {
        f32x4 c = {};
        c = __builtin_amdgcn_mfma_f32_16x16x32_bf16(kf[kj][0], aq[t][0], c, 0, 0, 0);
        c = __builtin_amdgcn_mfma_f32_16x16x32_bf16(kf[kj][1], aq[t][1], c, 0, 0, 0);
        sT[kj] = c;
      }
      // p = exp(s/8) (scores bounded -> no running-max rescale); local denom
#pragma unroll
      for (int kj = 0; kj < 4; ++kj) {
        const float p0 = __expf(sT[kj][0] * 0.125f);
        const float p1 = __expf(sT[kj][1] * 0.125f);
        const float p2 = __expf(sT[kj][2] * 0.125f);
        const float p3 = __expf(sT[kj][3] * 0.125f);
        lsum[t] += (p0 + p1) + (p2 + p3);
        P32[pwbase + kj * 8 + 0] = pack2bf(p0, p1);
        P32[pwbase + kj * 8 + 1] = pack2bf(p2, p3);
      }
      asm volatile("s_waitcnt lgkmcnt(0)" ::: "memory");
      ap[t][0] = *(const bf16x8*)(P + lm * 72 + quad * 8);
      ap[t][1] = *(const bf16x8*)(P + lm * 72 + 32 + quad * 8);
    }
    // PV with hoisted V fragments: O^T[d][q] += V^T[d][key] * P[q][key]
#pragma unroll
    for (int d4 = 0; d4 < 4; ++d4) {
      const int row = d4 * 16 + lm;
      const bf16x8 v0 = *(const bf16x8*)(Vs + row * 64 + ((quad) ^ (row & 7)) * 8);
      const bf16x8 v1 = *(const bf16x8*)(Vs + row * 64 + ((4 + quad) ^ (row & 7)) * 8);
#pragma unroll
      for (int t = 0; t < 2; ++t) {
        O[t][d4] = __builtin_amdgcn_mfma_f32_16x16x32_bf16(v0, ap[t][0], O[t][d4], 0, 0, 0);
        O[t][d4] = __builtin_amdgcn_mfma_f32_16x16x32_bf16(v1, ap[t][1], O[t][d4], 0, 0, 0);
      }
    }
  }
#pragma unroll
  for (int t = 0; t < 2; ++t) {
    float ls = lsum[t];
    ls += __shfl_xor(ls, 16);
    ls += __shfl_xor(ls, 32);
    const float inv = 1.0f / ls;  // per-lane correct for q = lm
#pragma unroll
    for (int d4 = 0; d4 < 4; ++d4) {
      uint2 pk;
      pk.x = pack2bf(O[t][d4][0] * inv, O[t][d4][1] * inv);
      pk.y = pack2bf(O[t][d4][2] * inv, O[t][d4][3] * inv);
      *(uint2*)(ctx + (pidx0 + t * 64) * 512 + h * 64 + d4 * 16 + quad * 4) = pk;
    }
  }
}

// ---------------- LN1 (routed): x1[p] = LN(x[tlist[p]] + ctxp[p]; g1,be1) -> bf16 ----------------
__global__ __launch_bounds__(256) void ln1_kernel(const float* __restrict__ x,
                                                  const u16* __restrict__ ctxp,
                                                  const float* __restrict__ g1,
                                                  const float* __restrict__ be1,
                                                  u16* __restrict__ x1,
                                                  const int* __restrict__ cnt,
                                                  const int* __restrict__ tlist) {
  const int i = blockIdx.x, b = blockIdx.y, e = blockIdx.z;
  const int seg = (e << 2) + b;
  const int ce = (cnt[seg] + 127) & ~127;
  if (i >= ce) return;  // compute all padded rows so downstream GEMM reads defined data
  const long long p = seg * 1024 + i;
  const int t = tlist[p];
  const int tid = threadIdx.x;
  const int wave = tid >> 6, lane = tid & 63;
  __shared__ float sred[4], qred[4];
  const float v0 = x[(long long)t * 512 + tid] + bf2f(ctxp[p * 512 + tid]);
  const float v1 = x[(long long)t * 512 + tid + 256] + bf2f(ctxp[p * 512 + tid + 256]);
  float s = v0 + v1, q = v0 * v0 + v1 * v1;
#pragma unroll
  for (int off = 32; off; off >>= 1) { s += __shfl_xor(s, off); q += __shfl_xor(q, off); }
  if (lane == 0) { sred[wave] = s; qred[wave] = q; }
  __syncthreads();
  s = sred[0] + sred[1] + sred[2] + sred[3];
  q = qred[0] + qred[1] + qred[2] + qred[3];
  const float mean = s * (1.0f / 512.0f);
  const float var = q * (1.0f / 512.0f) - mean * mean;
  const float rstd = rsqrtf(var + 1e-5f);
  x1[p * 512 + tid] = f2bf((v0 - mean) * rstd * g1[e * 512 + tid] + be1[e * 512 + tid]);
  x1[p * 512 + tid + 256] =
      f2bf((v1 - mean) * rstd * g1[e * 512 + tid + 256] + be1[e * 512 + tid + 256]);
}

// ---------------- LN2 + gate-weighted combine: out[t] = sum_e w[t,e]*LN(x1[p]+h2[p]) ----------------
__global__ __launch_bounds__(256) void ln2_kernel(const u16* __restrict__ x1,
                                                  const u16* __restrict__ h2,
                                                  const float* __restrict__ g2,
                                                  const float* __restrict__ be2,
                                                  const float* __restrict__ gated,
                                                  const int* __restrict__ pos,
                                                  float* __restrict__ out) {
  const int t = blockIdx.x, tid = threadIdx.x;
  const int b = t >> 10;
  const int wave = tid >> 6, lane = tid & 63;
  __shared__ float sred[4], qred[4];
  float o0 = 0.f, o1 = 0.f;
  for (int e = 0; e < 8; ++e) {
    const float wgt = gated[t * 8 + e];
    if (wgt != 0.f) {  // block-uniform branch (depends on t only)
      const long long p = ((e << 2) + b) * 1024 + pos[e * 4096 + t];
      const float v0 = bf2f(x1[p * 512 + tid]) + bf2f(h2[p * 512 + tid]);
      const float v1 = bf2f(x1[p * 512 + tid + 256]) + bf2f(h2[p * 512 + tid + 256]);
      float s = v0 + v1, q = v0 * v0 + v1 * v1;
#pragma unroll
      for (int off = 32; off; off >>= 1) { s += __shfl_xor(s, off); q += __shfl_xor(q, off); }
      if (lane == 0) { sred[wave] = s; qred[wave] = q; }
      __syncthreads();
      s = sred[0] + sred[1] + sred[2] + sred[3];
      q = qred[0] + qred[1] + qred[2] + qred[3];
      __syncthreads();
      const float mean = s * (1.0f / 512.0f);
      const float var = q * (1.0f / 512.0f) - mean * mean;
      const float rstd = rsqrtf(var + 1e-5f);
      o0 += wgt * ((v0 - mean) * rstd * g2[e * 512 + tid] + be2[e * 512 + tid]);
      o1 += wgt * ((v1 - mean) * rstd * g2[e * 512 + tid + 256] + be2[e * 512 + tid + 256]);
    }
  }
  out[(long long)t * 512 + tid] = o0;
  out[(long long)t * 512 + tid + 256] = o1;
}

// ---------------- launch ----------------
extern "C" void kernel_launch(void* const* d_in, const int* in_sizes, int n_in, void* d_out,
                              int out_size, void* d_ws, size_t ws_size, hipStream_t stream) {
  const float* x    = (const float*)d_in[0];
  const float* gWk  = (const float*)d_in[1];
  const float* gbk  = (const float*)d_in[2];
  const float* eq   = (const float*)d_in[3];
  const float* Wqkv = (const float*)d_in[4];
  const float* bqkv = (const float*)d_in[5];
  const float* Wo   = (const float*)d_in[6];
  const float* bo   = (const float*)d_in[7];
  const float* g1   = (const float*)d_in[8];
  const float* be1  = (const float*)d_in[9];
  const float* W1   = (const float*)d_in[10];
  const float* bf1  = (const float*)d_in[11];
  const float* W2   = (const float*)d_in[12];
  const float* bf2  = (const float*)d_in[13];
  const float* g2   = (const float*)d_in[14];
  const float* be2  = (const float*)d_in[15];
  float* out = (float*)d_out;

  char* wsp = (char*)d_ws;
  size_t off = 0;
  auto take = [&](size_t bytes) -> void* {
    void* p = wsp + off;
    off += (bytes + 255) & ~(size_t)255;
    return p;
  };
  u16* xb    = (u16*)take((size_t)Mc * 512 * 2);
  u16* Wqkvb = (u16*)take((size_t)Ec * 1536 * 512 * 2);
  u16* Wob   = (u16*)take((size_t)Ec * 512 * 512 * 2);
  u16* W1b   = (u16*)take((size_t)Ec * 2048 * 512 * 2);
  u16* W2b   = (u16*)take((size_t)Ec * 512 * 2048 * 2);
  float* weq   = (float*)take(8 * 512 * 4);
  float* beqb  = (float*)take(8 * 4);
  float* gated = (float*)take((size_t)Mc * 8 * 4);
  int* emask = (int*)take((size_t)Mc * 4);
  int* cnt   = (int*)take(32 * 4);
  int* tlist = (int*)take(32 * 1024 * 4);
  int* pos   = (int*)take((size_t)Ec * Mc * 4);
  int* wl    = (int*)take(1024 * 4);
  char* big = (char*)take(134217728);
  u16* qb   = (u16*)big;                  // compact q [32768][512], dead after attn
  u16* kb   = (u16*)(big + 33554432);     // k [E][M][512], dead after attn
  u16* vTb  = (u16*)(big + 67108864);     // [E][B][H][64][S], dead after attn
  u16* ctxp = (u16*)(big + 100663296);    // compact [32768][512], dead after ln1
  u16* hb   = (u16*)big;                  // compact [32768][2048], written after ln1
  u16* ctxb = (u16*)take(33554432);       // compact attn out, dead after Wo GEMM
  u16* h2b  = ctxb;                       // compact W2 out, written after W1
  u16* x1b  = (u16*)take(33554432);       // compact [32768][512]
  (void)in_sizes; (void)n_in; (void)out_size; (void)ws_size;

  // fp32 -> bf16 converts (single fused launch)
  cvt5_kernel<<<dim3(26624), dim3(256), 0, stream>>>(x, xb, Wqkv, Wqkvb, Wo, Wob, W1, W1b, W2, W2b);
  // gating (fp32 path; keys GEMM folded into weq precompute, beq folded into weq launch);
  // atomic-free two-pass routing
  weq_kernel<<<dim3(8, 8), dim3(256), 0, stream>>>(gWk, eq, gbk, weq, beqb);
  gate_kernel<<<dim3(1024), dim3(256), 0, stream>>>(x, weq, beqb, gated, emask);
  build_kernel<<<dim3(32), dim3(256), 0, stream>>>(emask, cnt, tlist, pos);
  wl_kernel<<<dim3(1), dim3(64), 0, stream>>>(cnt, wl);
  // k+v dense MERGED, double-buffered (61us dbuf vs 71us single-buffer, R12/R13).
  // grid (32,8,8); y<4 -> k into kb, y>=4 -> v (swapped ops) into vT.
  gemm_bf16<0, 2, 0, 64, 1><<<dim3(32, 8, 8), dim3(256), 0, stream>>>(
      xb, Wqkvb + 512 * 512, bqkv + 512, kb, vTb, Mc, 1024, 512, 0LL, 1536LL, wl);
  // q routed: 64-row tiles (BK=128), A rows gathered through tlist, compact output
  gemm64_bf16<0, 1, 128><<<dim3(192, 4), dim3(256), 0, stream>>>(
      xb, Wqkvb, bqkv, qb, 512, 512, 1536LL, wl, tlist);
  // attention: 1D grid, head in low 3 bits (head -> XCD pinning for K/V L2 reuse)
  attn_tile<<<dim3(96 * 8), dim3(256), 0, stream>>>(qb, kb, vTb, ctxb, wl);
  // Wo routed: 64-row tiles (BK=128)
  gemm64_bf16<0, 0, 128><<<dim3(192, 4), dim3(256), 0, stream>>>(
      ctxb, Wob, bo, ctxp, 512, 512, 512LL, wl, nullptr);
  ln1_kernel<<<dim3(1024, 4, 8), dim3(256), 0, stream>>>(x, ctxp, g1, be1, x1b, cnt, tlist);
  // W1 routed: expert->XCD-pinned grid (blockIdx.x = expert = linear id % 8), BK=64,
  // double-buffered (shallow pinned queue -> intra-block overlap is the latency cover).
  gemm_bf16<1, 0, 3, 64, 1><<<dim3(8, 32, 16), dim3(256), 0, stream>>>(
      x1b, W1b, bf1, hb, nullptr, Mc, 2048, 512, (long long)Mc * 512, 2048LL, wl);
  // W2 routed: 64-row tiles (BK=128), K=2048
  gemm64_bf16<1, 0, 128><<<dim3(192, 4), dim3(256), 0, stream>>>(
      hb, W2b, bf2, h2b, 512, 2048, 512LL, wl, nullptr);
  ln2_kernel<<<dim3(4096), dim3(256), 0, stream>>>(x1b, h2b, g2, be2, gated, pos, out);
}